// Round 1
// baseline (483.438 us; speedup 1.0000x reference)
//
#include <hip/hip_runtime.h>
#include <stdint.h>

// Problem constants (B,T,C,H,D) = (4,2048,1024,16,64)
#define Bb 4
#define Tt 2048
#define Cc 1024
#define Hh 16
#define Dd 64

using bf16x8 = __bf16 __attribute__((ext_vector_type(8)));
using f32x4  = float  __attribute__((ext_vector_type(4)));
typedef unsigned short u16;

__device__ __forceinline__ u16 f32_to_bf16(float f) {
  union { float f; unsigned u; } v; v.f = f;
  unsigned r = v.u + 0x7fffu + ((v.u >> 16) & 1u);  // RNE
  return (u16)(r >> 16);
}

// ---------------- cast fp32 -> bf16 (4 elem / thread) ----------------
__global__ void cast_f32_to_bf16(const float* __restrict__ in, u16* __restrict__ out, int n) {
  int i = (blockIdx.x * blockDim.x + threadIdx.x) * 4;
  if (i >= n) return;
  float4 v = *reinterpret_cast<const float4*>(in + i);
  ushort4 o;
  o.x = f32_to_bf16(v.x); o.y = f32_to_bf16(v.y);
  o.z = f32_to_bf16(v.z); o.w = f32_to_bf16(v.w);
  *reinterpret_cast<ushort4*>(out + i) = o;
}

// ---------------- GEMM: C[M,N] = A[M,K] * B[N,K]^T + bias ----------------
// A,B bf16 row-major; out bf16 or fp32. 128x128 tile, BK=32, 4 waves (2x2 of 64x64).
template<bool OUT_BF16>
__global__ __launch_bounds__(256, 2)
void gemm_bt(const u16* __restrict__ A, const u16* __restrict__ Bw,
             const float* __restrict__ bias, void* __restrict__ Cout,
             int M, int N, int K)
{
  constexpr int BK  = 32;
  constexpr int LDA = BK + 8;   // +16B pad: row-to-row bank shift of 20 -> conflict-free-ish
  __shared__ u16 As[128 * LDA];
  __shared__ u16 Bs[128 * LDA];
  const int tid  = threadIdx.x;
  const int wave = tid >> 6, lane = tid & 63;
  const int row0 = blockIdx.x * 128, col0 = blockIdx.y * 128;
  const int wm = (wave & 1) * 64, wn = (wave >> 1) * 64;
  const int fr = lane & 15, fk = (lane >> 4) * 8;
  const int srow = tid >> 2, scol = (tid & 3) * 8;

  f32x4 acc[4][4] = {};

  for (int k0 = 0; k0 < K; k0 += BK) {
#pragma unroll
    for (int c = 0; c < 2; ++c) {
      int r = c * 64 + srow;
      *reinterpret_cast<uint4*>(&As[r * LDA + scol]) =
          *reinterpret_cast<const uint4*>(A + (size_t)(row0 + r) * K + k0 + scol);
      *reinterpret_cast<uint4*>(&Bs[r * LDA + scol]) =
          *reinterpret_cast<const uint4*>(Bw + (size_t)(col0 + r) * K + k0 + scol);
    }
    __syncthreads();
    bf16x8 af[4], bf[4];
#pragma unroll
    for (int i = 0; i < 4; ++i) {
      af[i] = *reinterpret_cast<const bf16x8*>(&As[(wm + i * 16 + fr) * LDA + fk]);
      bf[i] = *reinterpret_cast<const bf16x8*>(&Bs[(wn + i * 16 + fr) * LDA + fk]);
    }
#pragma unroll
    for (int i = 0; i < 4; ++i)
#pragma unroll
      for (int j = 0; j < 4; ++j)
        acc[i][j] = __builtin_amdgcn_mfma_f32_16x16x32_bf16(af[i], bf[j], acc[i][j], 0, 0, 0);
    __syncthreads();
  }

  // Epilogue: C/D layout is col=lane&15, row=(lane>>4)*4+reg (m89-verified).
#pragma unroll
  for (int j = 0; j < 4; ++j) {
    int col = col0 + wn + j * 16 + fr;
    float bv = bias[col];
#pragma unroll
    for (int i = 0; i < 4; ++i) {
      int rowb = row0 + wm + i * 16 + (lane >> 4) * 4;
#pragma unroll
      for (int r = 0; r < 4; ++r) {
        float v = acc[i][j][r] + bv;
        size_t idx = (size_t)(rowb + r) * N + col;
        if (OUT_BF16) reinterpret_cast<u16*>(Cout)[idx] = f32_to_bf16(v);
        else          reinterpret_cast<float*>(Cout)[idx] = v;
      }
    }
  }
}

// ---------------- transpose v [B,T,C] -> VT [B,H,D,T] ----------------
__global__ __launch_bounds__(256)
void transpose_v(const u16* __restrict__ V, u16* __restrict__ VT) {
  __shared__ u16 Ts[64 * 72];
  const int tid = threadIdx.x;
  const int tt = blockIdx.x, bh = blockIdx.y;
  const int b = bh >> 4, h = bh & 15;
  const size_t vbase = (size_t)b * Tt * Cc + (size_t)h * Dd + (size_t)tt * 64 * Cc;
#pragma unroll
  for (int it = 0; it < 2; ++it) {
    int c = it * 256 + tid;
    int r = c >> 3, cc = (c & 7) * 8;
    *reinterpret_cast<uint4*>(&Ts[r * 72 + cc]) =
        *reinterpret_cast<const uint4*>(V + vbase + (size_t)r * Cc + cc);
  }
  __syncthreads();
  const size_t obase = (size_t)bh * Dd * Tt + (size_t)tt * 64;
#pragma unroll
  for (int it = 0; it < 2; ++it) {
    int c = it * 256 + tid;
    int dd = c >> 3, cc = (c & 7) * 8;
    alignas(16) u16 tmp[8];
#pragma unroll
    for (int j = 0; j < 8; ++j) tmp[j] = Ts[(cc + j) * 72 + dd];
    *reinterpret_cast<uint4*>(VT + obase + (size_t)dd * Tt + cc) =
        *reinterpret_cast<const uint4*>(tmp);
  }
}

// ---------------- flash attention ----------------
// grid (T/64, B*H), 256 threads. Wave w owns q-rows [qt*64+w*16, +16).
// K,V^T staged in LDS per 64-key tile; P transits LDS (C-layout -> A-layout).
__global__ __launch_bounds__(256, 2)
void attn_kernel(const u16* __restrict__ Q, const u16* __restrict__ Kmat,
                 const u16* __restrict__ VT, u16* __restrict__ O) {
  constexpr int LDK = 72, LDV = 72, LDP = 72;
  __shared__ u16 Ks[64 * LDK];   // [key][d]
  __shared__ u16 Vs[64 * LDV];   // [d][key]  (from VT)
  __shared__ u16 Ps[4 * 16 * LDP];
  const int tid = threadIdx.x, wave = tid >> 6, lane = tid & 63;
  const int qt = blockIdx.x, bh = blockIdx.y;
  const int b = bh >> 4, h = bh & 15;
  const size_t base = (size_t)b * Tt * Cc + (size_t)h * Dd;
  const int q0 = qt * 64 + wave * 16;
  const int fr = lane & 15, fk = (lane >> 4) * 8;

  // Q fragments (A-layout), loaded once
  bf16x8 aq0 = *reinterpret_cast<const bf16x8*>(Q + base + (size_t)(q0 + fr) * Cc + fk);
  bf16x8 aq1 = *reinterpret_cast<const bf16x8*>(Q + base + (size_t)(q0 + fr) * Cc + 32 + fk);

  f32x4 Oacc[4] = {};
  float mrow[4] = {-1e30f, -1e30f, -1e30f, -1e30f};
  float lrow[4] = {0.f, 0.f, 0.f, 0.f};
  const float SCL = 0.125f;          // 1/sqrt(64)
  const float L2E = 1.44269504f;
  const size_t vtb = (size_t)bh * Dd * Tt;
  u16* Pw = &Ps[wave * 16 * LDP];

  for (int kt = 0; kt < Tt; kt += 64) {
#pragma unroll
    for (int it = 0; it < 2; ++it) {
      int c = it * 256 + tid;
      int r = c >> 3, cc = (c & 7) * 8;
      *reinterpret_cast<uint4*>(&Ks[r * LDK + cc]) =
          *reinterpret_cast<const uint4*>(Kmat + base + (size_t)(kt + r) * Cc + cc);
      *reinterpret_cast<uint4*>(&Vs[r * LDV + cc]) =
          *reinterpret_cast<const uint4*>(VT + vtb + (size_t)r * Tt + kt + cc);
    }
    __syncthreads();

    // S = Q K^T  (16 q-rows x 64 keys, scaled)
    f32x4 s[4];
#pragma unroll
    for (int j = 0; j < 4; ++j) {
      bf16x8 bk0 = *reinterpret_cast<const bf16x8*>(&Ks[(j * 16 + fr) * LDK + fk]);
      bf16x8 bk1 = *reinterpret_cast<const bf16x8*>(&Ks[(j * 16 + fr) * LDK + 32 + fk]);
      f32x4 z = {};
      z    = __builtin_amdgcn_mfma_f32_16x16x32_bf16(aq0, bk0, z, 0, 0, 0);
      s[j] = __builtin_amdgcn_mfma_f32_16x16x32_bf16(aq1, bk1, z, 0, 0, 0);
    }
#pragma unroll
    for (int j = 0; j < 4; ++j) s[j] *= SCL;

    // online softmax; row = (lane>>4)*4 + r, key-col = j*16 + (lane&15)
#pragma unroll
    for (int r = 0; r < 4; ++r) {
      float mx = fmaxf(fmaxf(s[0][r], s[1][r]), fmaxf(s[2][r], s[3][r]));
#pragma unroll
      for (int off = 1; off < 16; off <<= 1) mx = fmaxf(mx, __shfl_xor(mx, off, 64));
      float mn = fmaxf(mrow[r], mx);
      float sum = 0.f;
#pragma unroll
      for (int j = 0; j < 4; ++j) {
        float p = exp2f((s[j][r] - mn) * L2E);
        s[j][r] = p; sum += p;
      }
#pragma unroll
      for (int off = 1; off < 16; off <<= 1) sum += __shfl_xor(sum, off, 64);
      float alpha = exp2f((mrow[r] - mn) * L2E);   // first iter: exp2(-huge) = 0
      lrow[r] = lrow[r] * alpha + sum;
      mrow[r] = mn;
#pragma unroll
      for (int n = 0; n < 4; ++n) Oacc[n][r] *= alpha;
    }

    // P: C-layout -> LDS -> A-layout
#pragma unroll
    for (int j = 0; j < 4; ++j)
#pragma unroll
      for (int r = 0; r < 4; ++r)
        Pw[((lane >> 4) * 4 + r) * LDP + j * 16 + fr] = f32_to_bf16(s[j][r]);

    __syncthreads();  // also guards against compiler reordering the cross-lane LDS use

#pragma unroll
    for (int kk = 0; kk < 2; ++kk) {
      bf16x8 ap = *reinterpret_cast<const bf16x8*>(&Pw[fr * LDP + kk * 32 + fk]);
#pragma unroll
      for (int n = 0; n < 4; ++n) {
        bf16x8 bv = *reinterpret_cast<const bf16x8*>(&Vs[(n * 16 + fr) * LDV + kk * 32 + fk]);
        Oacc[n] = __builtin_amdgcn_mfma_f32_16x16x32_bf16(ap, bv, Oacc[n], 0, 0, 0);
      }
    }
    __syncthreads();  // before next tile overwrites Ks/Vs
  }

#pragma unroll
  for (int r = 0; r < 4; ++r) {
    float linv = 1.0f / lrow[r];
    int t = q0 + (lane >> 4) * 4 + r;
#pragma unroll
    for (int n = 0; n < 4; ++n)
      O[base + (size_t)t * Cc + n * 16 + fr] = f32_to_bf16(Oacc[n][r] * linv);
  }
}

extern "C" void kernel_launch(void* const* d_in, const int* in_sizes, int n_in,
                              void* d_out, int out_size, void* d_ws, size_t ws_size,
                              hipStream_t stream) {
  const float* x  = (const float*)d_in[0];
  const float* Wq = (const float*)d_in[1];
  const float* bq = (const float*)d_in[2];
  const float* Wk = (const float*)d_in[3];
  const float* bk = (const float*)d_in[4];
  const float* Wv = (const float*)d_in[5];
  const float* bv = (const float*)d_in[6];
  const float* Wo = (const float*)d_in[7];
  const float* bo = (const float*)d_in[8];

  const size_t NX = (size_t)Bb * Tt * Cc;  // 8388608
  const size_t NW = (size_t)Cc * Cc;       // 1048576

  // ws layout (u16 elements), total 75.5 MB:
  // [xb | wq wk wv wo | q | k | v]; vt aliases xb (x dead after projections);
  // attn aliases v (v dead after transpose).
  u16* ws  = (u16*)d_ws;
  u16* xb  = ws;
  u16* wqb = ws + NX;
  u16* wkb = wqb + NW;
  u16* wvb = wkb + NW;
  u16* wob = wvb + NW;
  u16* qb  = wob + NW;
  u16* kb  = qb + NX;
  u16* vb  = kb + NX;
  u16* vtb   = xb;  // alias
  u16* attnb = vb;  // alias

  cast_f32_to_bf16<<<(int)(NX / 4 / 256), 256, 0, stream>>>(x,  xb,  (int)NX);
  cast_f32_to_bf16<<<(int)(NW / 4 / 256), 256, 0, stream>>>(Wq, wqb, (int)NW);
  cast_f32_to_bf16<<<(int)(NW / 4 / 256), 256, 0, stream>>>(Wk, wkb, (int)NW);
  cast_f32_to_bf16<<<(int)(NW / 4 / 256), 256, 0, stream>>>(Wv, wvb, (int)NW);
  cast_f32_to_bf16<<<(int)(NW / 4 / 256), 256, 0, stream>>>(Wo, wob, (int)NW);

  dim3 gg(64, 8);
  gemm_bt<true><<<gg, 256, 0, stream>>>(xb, wqb, bq, qb, Bb * Tt, Cc, Cc);
  gemm_bt<true><<<gg, 256, 0, stream>>>(xb, wkb, bk, kb, Bb * Tt, Cc, Cc);
  gemm_bt<true><<<gg, 256, 0, stream>>>(xb, wvb, bv, vb, Bb * Tt, Cc, Cc);

  transpose_v<<<dim3(Tt / 64, Bb * Hh), 256, 0, stream>>>(vb, vtb);

  attn_kernel<<<dim3(Tt / 64, Bb * Hh), 256, 0, stream>>>(qb, kb, vtb, attnb);

  gemm_bt<false><<<gg, 256, 0, stream>>>(attnb, wob, bo, d_out, Bb * Tt, Cc, Cc);
}